// Round 1
// baseline (2074.508 us; speedup 1.0000x reference)
//
#include <hip/hip_runtime.h>
#include <math.h>

#define ACT_NONE 0
#define ACT_RELU 1
#define ACT_SIG  2

// Generic direct 3x3x3 conv, pad=1, optional fused nearest-upsample concat:
// input channels [0, CIUP) come from `up` at half resolution (D/2)^3,
// channels [CIUP, CI) from `src` at full resolution D^3.
// Each thread computes 4 consecutive W outputs for COC output channels.
// Weights staged in LDS as [ci_local][tap][co] so the co loop reads b128.
template<int CI, int CO, int CIUP, int D, int COC, int CIC, int ACT, bool BIAS>
__global__ __launch_bounds__(256) void conv3k(
    const float* __restrict__ up, const float* __restrict__ src,
    const float* __restrict__ wgt, const float* __restrict__ bias,
    float* __restrict__ out)
{
    constexpr int WQ = (D == 32) ? 8 : (D == 16) ? 4 : 2;
    constexpr int TH = (D == 32) ? 32 : (D == 16) ? 16 : 8;
    constexpr int TD = (D == 32) ? 1 : (D == 16) ? 4 : 8;
    constexpr int NT = WQ * TH * TD;        // 256 / 256 / 128
    constexpr int DBLK = D / TD;            // blocks along depth per sample
    constexpr int CISRC = CI - CIUP;
    constexpr int DH = D / 2;

    __shared__ float sw[CIC * 27 * COC];

    const int tid = threadIdx.x;
    const int wq = tid % WQ;
    const int h  = (tid / WQ) % TH;
    const int dz = tid / (WQ * TH);
    const int w0 = wq * 4;

    const int bx   = blockIdx.x;
    const int n    = bx / DBLK;
    const int dblk = bx % DBLK;
    const int d    = dblk * TD + dz;
    const int cob  = blockIdx.y * COC;

    float acc[COC][4];
#pragma unroll
    for (int co = 0; co < COC; ++co) {
        float b0 = 0.f;
        if (BIAS) { int cg = cob + co; if (cg < CO) b0 = bias[cg]; }
        acc[co][0] = b0; acc[co][1] = b0; acc[co][2] = b0; acc[co][3] = b0;
    }

    for (int cib = 0; cib < CI; cib += CIC) {
        __syncthreads();
        // stage weight chunk: lds[(cil*27 + tap)*COC + co] = w[cob+co][cib+cil][tap]
        for (int t = tid; t < CIC * 27 * COC; t += NT) {
            int co  = t % COC;
            int r   = t / COC;
            int tap = r % 27;
            int cil = r / 27;
            int cg  = cob + co;
            float v = 0.f;
            if (cg < CO) v = wgt[((size_t)cg * CI + (cib + cil)) * 27 + tap];
            sw[t] = v;
        }
        __syncthreads();

        for (int cil = 0; cil < CIC; ++cil) {
            const int ci = cib + cil;
#pragma unroll
            for (int kd = 0; kd < 3; ++kd) {
                int zd = d + kd - 1;
                if ((unsigned)zd >= (unsigned)D) continue;
#pragma unroll
                for (int kh = 0; kh < 3; ++kh) {
                    int zh = h + kh - 1;
                    if ((unsigned)zh >= (unsigned)D) continue;
                    float v[6];
                    if (CIUP > 0 && ci < CIUP) {
                        const float* p = up +
                            (((size_t)(n * CIUP + ci) * DH + (zd >> 1)) * DH + (zh >> 1)) * DH;
#pragma unroll
                        for (int j = 0; j < 6; ++j) {
                            int zw = w0 - 1 + j;
                            v[j] = ((unsigned)zw < (unsigned)D) ? p[zw >> 1] : 0.f;
                        }
                    } else {
                        const float* p = src +
                            (((size_t)(n * CISRC + (ci - CIUP)) * D + zd) * D + zh) * D;
#pragma unroll
                        for (int j = 0; j < 6; ++j) {
                            int zw = w0 - 1 + j;
                            v[j] = ((unsigned)zw < (unsigned)D) ? p[zw] : 0.f;
                        }
                    }
                    const float* swp = &sw[(cil * 27 + kd * 9 + kh * 3) * COC];
#pragma unroll
                    for (int kw = 0; kw < 3; ++kw) {
#pragma unroll
                        for (int co = 0; co < COC; ++co) {
                            float wv = swp[kw * COC + co];
#pragma unroll
                            for (int j = 0; j < 4; ++j)
                                acc[co][j] = fmaf(v[kw + j], wv, acc[co][j]);
                        }
                    }
                }
            }
        }
    }

#pragma unroll
    for (int co = 0; co < COC; ++co) {
        int cg = cob + co;
        if (cg < CO) {
            float* op = out + (((size_t)(n * CO + cg) * D + d) * D + h) * D + w0;
#pragma unroll
            for (int j = 0; j < 4; ++j) {
                float x = acc[co][j];
                if (ACT == ACT_RELU) x = fmaxf(x, 0.f);
                else if (ACT == ACT_SIG) x = 1.f / (1.f + expf(-x));
                op[j] = x;
            }
        }
    }
}

__global__ __launch_bounds__(256) void maxpoolk(
    const float* __restrict__ in, float* __restrict__ out, int total, int Do)
{
    int t = blockIdx.x * blockDim.x + threadIdx.x;
    if (t >= total) return;
    int w = t % Do; int r = t / Do;
    int h = r % Do; r /= Do;
    int d = r % Do; int nc = r / Do;
    int Di = Do * 2;
    const float* p = in + (((size_t)nc * Di + 2 * d) * Di + 2 * h) * Di + 2 * w;
    float m = fmaxf(p[0], p[1]);
    m = fmaxf(m, fmaxf(p[Di], p[Di + 1]));
    const float* q = p + (size_t)Di * Di;
    m = fmaxf(m, fmaxf(q[0], q[1]));
    m = fmaxf(m, fmaxf(q[Di], q[Di + 1]));
    out[t] = m;
}

// per level: hsum[p] = h[child0]+h[child1];  cred[p] = f[2p]*c[child0] + f[2p+1]*c[child1]
__global__ __launch_bounds__(256) void treereduce(
    const float* __restrict__ h_all, const float* __restrict__ c_all,
    const float* __restrict__ f, float* __restrict__ hsum,
    float* __restrict__ cred, int P, int cb)
{
    int t = blockIdx.x * blockDim.x + threadIdx.x;
    if (t >= P * 5120) return;
    int p = t / 5120, r = t % 5120;
    size_t ci0 = (size_t)(cb + 2 * p) * 5120 + r;
    size_t ci1 = ci0 + 5120;
    hsum[t] = h_all[ci0] + h_all[ci1];
    cred[t] = f[(size_t)(2 * p) * 5120 + r] * c_all[ci0] +
              f[(size_t)(2 * p + 1) * 5120 + r] * c_all[ci1];
}

// LSTM cell: i,o,u = split(iou + b_iou); c = sig(i)*tanh(u) + cin; h = sig(o)*tanh(c)
__global__ __launch_bounds__(256) void treeapply(
    const float* __restrict__ iou, const float* __restrict__ b_iou,
    const float* __restrict__ cin, float* __restrict__ h_all,
    float* __restrict__ c_all, int P, int nodeBase)
{
    int t = blockIdx.x * blockDim.x + threadIdx.x;
    if (t >= P * 512) return;
    int p = t / 512, s = t % 512;
    const float* ip = iou + (size_t)p * 30 * 512 + s;
    const float* cp = cin + (size_t)p * 10 * 512 + s;
    float* hp = h_all + (size_t)(nodeBase + p) * 10 * 512 + s;
    float* co = c_all + (size_t)(nodeBase + p) * 10 * 512 + s;
#pragma unroll
    for (int ch = 0; ch < 10; ++ch) {
        float i = ip[(size_t)ch * 512]        + b_iou[(size_t)ch * 512 + s];
        float o = ip[(size_t)(10 + ch) * 512] + b_iou[(size_t)(10 + ch) * 512 + s];
        float u = ip[(size_t)(20 + ch) * 512] + b_iou[(size_t)(20 + ch) * 512 + s];
        float si = 1.f / (1.f + expf(-i));
        float so = 1.f / (1.f + expf(-o));
        float c = si * tanhf(u) + cp[(size_t)ch * 512];
        float h = so * tanhf(c);
        hp[(size_t)ch * 512] = h;
        co[(size_t)ch * 512] = c;
    }
}

// d1c: 1x1x1 conv 16->1 with bias, pad=0
__global__ __launch_bounds__(256) void conv1x1(
    const float* __restrict__ in, const float* __restrict__ w,
    const float* __restrict__ b, float* __restrict__ out, int total)
{
    int t = blockIdx.x * blockDim.x + threadIdx.x;
    if (t >= total) return;
    int n = t / 32768, s = t % 32768;
    const float* p = in + (size_t)n * 16 * 32768 + s;
    float a = b[0];
#pragma unroll
    for (int c = 0; c < 16; ++c) a = fmaf(w[c], p[(size_t)c * 32768], a);
    out[t] = a;
}

extern "C" void kernel_launch(void* const* d_in, const int* in_sizes, int n_in,
                              void* d_out, int out_size, void* d_ws, size_t ws_size,
                              hipStream_t stream)
{
    const float* data  = (const float*)d_in[0];
    // d_in[1] = h0 (unused by reference)
    const float* c0    = (const float*)d_in[2];
    const float* e1a_w = (const float*)d_in[3];  const float* e1a_b = (const float*)d_in[4];
    const float* e1b_w = (const float*)d_in[5];  const float* e1b_b = (const float*)d_in[6];
    const float* e2a_w = (const float*)d_in[7];  const float* e2a_b = (const float*)d_in[8];
    const float* e2b_w = (const float*)d_in[9];  const float* e2b_b = (const float*)d_in[10];
    const float* d2a_w = (const float*)d_in[11]; const float* d2a_b = (const float*)d_in[12];
    const float* d2b_w = (const float*)d_in[13]; const float* d2b_b = (const float*)d_in[14];
    const float* d1a_w = (const float*)d_in[15]; const float* d1a_b = (const float*)d_in[16];
    const float* d1b_w = (const float*)d_in[17]; const float* d1b_b = (const float*)d_in[18];
    const float* d1c_w = (const float*)d_in[19]; const float* d1c_b = (const float*)d_in[20];
    const float* w_iou = (const float*)d_in[21];
    const float* u_iou = (const float*)d_in[22];
    const float* u_f   = (const float*)d_in[23];
    const float* b_iou = (const float*)d_in[24];

    float* ws = (float*)d_ws;
    size_t o = 0;
    float* t1   = ws + o; o += 16252928;   // [31,16,32^3]  (reused as t4)
    float* x0   = ws + o; o += 16252928;   // [31,16,32^3]  (reused as t5)
    float* xp   = ws + o; o += 2031616;    // [31,16,16^3]
    float* t2   = ws + o; o += 4063232;    // [31,32,16^3]  (reused as t3 [31,20,16^3])
    float* x1   = ws + o; o += 2539520;    // [31,20,16^3]
    float* xp2  = ws + o; o += 317440;     // [31,20,8^3]
    float* Wx   = ws + o; o += 245760;     // [16,30,8^3] leaves only
    float* h_all= ws + o; o += 158720;     // [31,10,8^3]
    float* c_all= ws + o; o += 158720;
    float* f_buf= ws + o; o += 81920;      // [16,10,8^3] max
    float* hsum = ws + o; o += 40960;      // [8,10,8^3] max
    float* cred = ws + o; o += 40960;
    float* ioub = ws + o; o += 122880;     // [8,30,8^3] max
    float* y2   = ws + o; o += 4063232;    // [31,32,16^3]
    float* t3 = t2;
    float* t4 = t1;
    float* t5 = x0;
    (void)ws_size; (void)in_sizes; (void)n_in; (void)out_size;

    dim3 b256(256), b128(128);

    // ---- Encoder ----
    conv3k<1, 16, 0, 32, 16, 1, ACT_RELU, true>
        <<<dim3(31 * 32, 1), b256, 0, stream>>>(nullptr, data, e1a_w, e1a_b, t1);
    conv3k<16, 16, 0, 32, 16, 16, ACT_RELU, true>
        <<<dim3(31 * 32, 1), b256, 0, stream>>>(nullptr, t1, e1b_w, e1b_b, x0);
    maxpoolk<<<dim3((2031616 + 255) / 256), b256, 0, stream>>>(x0, xp, 2031616, 16);
    conv3k<16, 32, 0, 16, 16, 16, ACT_RELU, true>
        <<<dim3(31 * 4, 2), b256, 0, stream>>>(nullptr, xp, e2a_w, e2a_b, t2);
    conv3k<32, 20, 0, 16, 10, 16, ACT_RELU, true>
        <<<dim3(31 * 4, 2), b256, 0, stream>>>(nullptr, t2, e2b_w, e2b_b, x1);
    maxpoolk<<<dim3((317440 + 255) / 256), b256, 0, stream>>>(x1, xp2, 317440, 8);

    // ---- W_iou for leaves (nodes 15..30) ----
    conv3k<20, 30, 0, 8, 15, 10, ACT_NONE, false>
        <<<dim3(16, 2), b128, 0, stream>>>(nullptr, xp2 + (size_t)15 * 20 * 512, w_iou, nullptr, Wx);
    treeapply<<<dim3((16 * 512 + 255) / 256), b256, 0, stream>>>(
        Wx, b_iou, c0 + (size_t)15 * 10 * 512, h_all, c_all, 16, 15);

    // ---- internal levels, bottom-up ----
    for (int lvl = 3; lvl >= 0; --lvl) {
        int P  = 1 << lvl;
        int cb = (1 << (lvl + 1)) - 1;   // child base (contiguous 2P nodes)
        int pb = (1 << lvl) - 1;         // parent base
        conv3k<10, 10, 0, 8, 10, 10, ACT_SIG, false>
            <<<dim3(2 * P, 1), b128, 0, stream>>>(nullptr, h_all + (size_t)cb * 5120, u_f, nullptr, f_buf);
        treereduce<<<dim3((P * 5120 + 255) / 256), b256, 0, stream>>>(
            h_all, c_all, f_buf, hsum, cred, P, cb);
        conv3k<10, 30, 0, 8, 15, 10, ACT_NONE, false>
            <<<dim3(P, 2), b128, 0, stream>>>(nullptr, hsum, u_iou, nullptr, ioub);
        treeapply<<<dim3((P * 512 + 255) / 256), b256, 0, stream>>>(
            ioub, b_iou, cred, h_all, c_all, P, pb);
    }

    // ---- Decoder (fused up2 + concat in conv fetch) ----
    conv3k<30, 20, 10, 16, 10, 10, ACT_RELU, true>
        <<<dim3(31 * 4, 2), b256, 0, stream>>>(h_all, x1, d2a_w, d2a_b, t3);
    conv3k<20, 32, 0, 16, 16, 10, ACT_RELU, true>
        <<<dim3(31 * 4, 2), b256, 0, stream>>>(nullptr, t3, d2b_w, d2b_b, y2);
    conv3k<48, 16, 32, 32, 16, 16, ACT_RELU, true>
        <<<dim3(31 * 32, 1), b256, 0, stream>>>(y2, x0, d1a_w, d1a_b, t4);
    conv3k<16, 16, 0, 32, 16, 16, ACT_RELU, true>
        <<<dim3(31 * 32, 1), b256, 0, stream>>>(nullptr, t4, d1b_w, d1b_b, t5);
    conv1x1<<<dim3((31 * 32768 + 255) / 256), b256, 0, stream>>>(
        t5, d1c_w, d1c_b, (float*)d_out, 31 * 32768);
}

// Round 3
// 1402.523 us; speedup vs baseline: 1.4791x; 1.4791x over previous
//
#include <hip/hip_runtime.h>
#include <math.h>

#define ACT_NONE 0
#define ACT_RELU 1
#define ACT_SIG  2

typedef _Float16 h2 __attribute__((ext_vector_type(2)));

__device__ inline h2 uph(unsigned u) { return __builtin_bit_cast(h2, u); }
__device__ inline unsigned pkh(float a, float b) {
    return __builtin_bit_cast(unsigned, __builtin_amdgcn_cvt_pkrtz(a, b));
}
__device__ inline float dot2(unsigned a, unsigned b, float c) {
    return __builtin_amdgcn_fdot2(uph(a), uph(b), c, false);
}

// Direct 3x3x3 conv, pad=1, activations stored as channel-paired half2 (u32).
// CIP = input channel pairs; CIUPP pairs come from `up` at half resolution
// (fused nearest-upsample+concat); weights (fp32 global) packed to half2
// pairs in LDS as [cip_local][tap][co]. Each thread: 4 consecutive W outputs
// x COC output channels, f32 accumulation via v_dot2_f32_f16.
template<int CIP, int CO, int CIUPP, int D, int COC, int CICP, int ACT, bool BIAS>
__global__ __launch_bounds__(256) void conv3h(
    const unsigned* __restrict__ up, const unsigned* __restrict__ src,
    const float* __restrict__ wgt, const float* __restrict__ bias,
    unsigned* __restrict__ out)
{
    constexpr int WQ = (D == 32) ? 8 : (D == 16) ? 4 : 2;
    constexpr int TH = (D == 32) ? 32 : (D == 16) ? 16 : 8;
    constexpr int TD = (D == 32) ? 1 : (D == 16) ? 4 : 8;
    constexpr int NT = WQ * TH * TD;        // 256 / 256 / 128
    constexpr int DBLK = D / TD;
    constexpr int CI = CIP * 2;             // full channels (weight tensor dim)
    constexpr int DH = D / 2;

    __shared__ unsigned sw[CICP * 27 * COC];

    const int tid = threadIdx.x;
    const int wq = tid % WQ;
    const int h  = (tid / WQ) % TH;
    const int dz = tid / (WQ * TH);
    const int w0 = wq * 4;

    const int bx   = blockIdx.x;
    const int n    = bx / DBLK;
    const int dblk = bx % DBLK;
    const int d    = dblk * TD + dz;
    const int cob  = blockIdx.y * COC;

    float acc[COC][4];
#pragma unroll
    for (int co = 0; co < COC; ++co) {
        float b0 = 0.f;
        if (BIAS) { int cg = cob + co; if (cg < CO) b0 = bias[cg]; }
        acc[co][0] = b0; acc[co][1] = b0; acc[co][2] = b0; acc[co][3] = b0;
    }

    for (int cib = 0; cib < CIP; cib += CICP) {
        __syncthreads();
        // stage weight pair chunk: sw[(cilp*27+tap)*COC+co] = pack(w[cg][2cip][tap], w[cg][2cip+1][tap])
        for (int t = tid; t < CICP * 27 * COC; t += NT) {
            int co   = t % COC;
            int r    = t / COC;
            int tap  = r % 27;
            int cilp = r / 27;
            int cg   = cob + co;
            int ci0  = 2 * (cib + cilp);
            unsigned v = 0;
            if (cg < CO) {
                float w0f = wgt[((size_t)cg * CI + ci0) * 27 + tap];
                float w1f = wgt[((size_t)cg * CI + ci0 + 1) * 27 + tap];
                v = pkh(w0f, w1f);
            }
            sw[t] = v;
        }
        __syncthreads();

        for (int cilp = 0; cilp < CICP; ++cilp) {
            const int cip = cib + cilp;
#pragma unroll
            for (int kd = 0; kd < 3; ++kd) {
                int zd = d + kd - 1;
                if ((unsigned)zd >= (unsigned)D) continue;
#pragma unroll
                for (int kh = 0; kh < 3; ++kh) {
                    int zh = h + kh - 1;
                    if ((unsigned)zh >= (unsigned)D) continue;
                    unsigned v[6];
                    if (CIUPP > 0 && cip < CIUPP) {
                        const unsigned* p = up +
                            (((size_t)(n * CIUPP + cip) * DH + (zd >> 1)) * DH + (zh >> 1)) * DH;
#pragma unroll
                        for (int j = 0; j < 6; ++j) {
                            int zw = w0 - 1 + j;
                            v[j] = ((unsigned)zw < (unsigned)D) ? p[zw >> 1] : 0u;
                        }
                    } else {
                        const unsigned* p = src +
                            (((size_t)(n * (CIP - CIUPP) + (cip - CIUPP)) * D + zd) * D + zh) * D;
#pragma unroll
                        for (int j = 0; j < 6; ++j) {
                            int zw = w0 - 1 + j;
                            v[j] = ((unsigned)zw < (unsigned)D) ? p[zw] : 0u;
                        }
                    }
                    const unsigned* swp = &sw[(cilp * 27 + kd * 9 + kh * 3) * COC];
#pragma unroll
                    for (int kw = 0; kw < 3; ++kw) {
#pragma unroll
                        for (int co = 0; co < COC; ++co) {
                            unsigned wv = swp[kw * COC + co];
#pragma unroll
                            for (int j = 0; j < 4; ++j)
                                acc[co][j] = dot2(v[kw + j], wv, acc[co][j]);
                        }
                    }
                }
            }
        }
    }

#pragma unroll
    for (int cp = 0; cp < COC / 2; ++cp) {
        int cg = cob + 2 * cp;
        if (cg < CO) {
            unsigned r[4];
#pragma unroll
            for (int j = 0; j < 4; ++j) {
                float x0 = acc[2 * cp][j], x1 = acc[2 * cp + 1][j];
                if (ACT == ACT_RELU) { x0 = fmaxf(x0, 0.f); x1 = fmaxf(x1, 0.f); }
                else if (ACT == ACT_SIG) {
                    x0 = 1.f / (1.f + expf(-x0)); x1 = 1.f / (1.f + expf(-x1));
                }
                r[j] = pkh(x0, x1);
            }
            unsigned* op = out + ((size_t)(n * (CO / 2) + (cg >> 1)) * D + d) * D * D + h * D + w0;
            *reinterpret_cast<uint4*>(op) = make_uint4(r[0], r[1], r[2], r[3]);
        }
    }
}

// e1a: 1 fp32 input channel -> 16 channels (8 pairs packed), D=32
__global__ __launch_bounds__(256) void conv3e1a(
    const float* __restrict__ src, const float* __restrict__ wgt,
    const float* __restrict__ bias, unsigned* __restrict__ out)
{
    __shared__ float sw[27 * 16];
    const int tid = threadIdx.x;
    const int wq = tid % 8;
    const int h  = (tid / 8) % 32;
    const int w0 = wq * 4;
    const int n  = blockIdx.x / 32;
    const int d  = blockIdx.x % 32;

    for (int t = tid; t < 27 * 16; t += 256) {
        int co = t % 16, tap = t / 16;
        sw[t] = wgt[(size_t)co * 27 + tap];
    }
    __syncthreads();

    float acc[16][4];
#pragma unroll
    for (int co = 0; co < 16; ++co) {
        float b0 = bias[co];
        acc[co][0] = b0; acc[co][1] = b0; acc[co][2] = b0; acc[co][3] = b0;
    }

#pragma unroll
    for (int kd = 0; kd < 3; ++kd) {
        int zd = d + kd - 1;
        if ((unsigned)zd >= 32u) continue;
#pragma unroll
        for (int kh = 0; kh < 3; ++kh) {
            int zh = h + kh - 1;
            if ((unsigned)zh >= 32u) continue;
            const float* p = src + ((size_t)n * 32 + zd) * 1024 + zh * 32;
            float v[6];
#pragma unroll
            for (int j = 0; j < 6; ++j) {
                int zw = w0 - 1 + j;
                v[j] = ((unsigned)zw < 32u) ? p[zw] : 0.f;
            }
            const float* swp = &sw[(kd * 9 + kh * 3) * 16];
#pragma unroll
            for (int kw = 0; kw < 3; ++kw)
#pragma unroll
                for (int co = 0; co < 16; ++co)
#pragma unroll
                    for (int j = 0; j < 4; ++j)
                        acc[co][j] = fmaf(v[kw + j], swp[kw * 16 + co], acc[co][j]);
        }
    }

#pragma unroll
    for (int cp = 0; cp < 8; ++cp) {
        unsigned r[4];
#pragma unroll
        for (int j = 0; j < 4; ++j)
            r[j] = pkh(fmaxf(acc[2 * cp][j], 0.f), fmaxf(acc[2 * cp + 1][j], 0.f));
        unsigned* op = out + ((size_t)(n * 8 + cp) * 32 + d) * 1024 + h * 32 + w0;
        *reinterpret_cast<uint4*>(op) = make_uint4(r[0], r[1], r[2], r[3]);
    }
}

// 2x2x2 maxpool on packed half2 arrays
__global__ __launch_bounds__(256) void maxpoolh(
    const unsigned* __restrict__ in, unsigned* __restrict__ out, int total, int Do)
{
    int t = blockIdx.x * blockDim.x + threadIdx.x;
    if (t >= total) return;
    int w = t % Do; int r = t / Do;
    int h = r % Do; r /= Do;
    int d = r % Do; int nc = r / Do;
    int Di = Do * 2;
    const unsigned* p = in + (((size_t)nc * Di + 2 * d) * Di + 2 * h) * Di + 2 * w;
    float m0 = -1e30f, m1 = -1e30f;
#pragma unroll
    for (int a = 0; a < 2; ++a)
#pragma unroll
        for (int b = 0; b < 2; ++b)
#pragma unroll
            for (int c = 0; c < 2; ++c) {
                h2 x = uph(p[((size_t)a * Di + b) * Di + c]);
                m0 = fmaxf(m0, (float)x.x);
                m1 = fmaxf(m1, (float)x.y);
            }
    out[t] = pkh(m0, m1);
}

// hsum[p] = h[c0]+h[c1]; cred[p] = f[2p]*c[c0] + f[2p+1]*c[c1]  (packed half2)
__global__ __launch_bounds__(256) void treereduceh(
    const unsigned* __restrict__ h_all, const unsigned* __restrict__ c_all,
    const unsigned* __restrict__ f, unsigned* __restrict__ hsum,
    unsigned* __restrict__ cred, int P, int cb)
{
    int t = blockIdx.x * blockDim.x + threadIdx.x;
    if (t >= P * 2560) return;
    int p = t / 2560, r = t % 2560;
    size_t i0 = (size_t)(cb + 2 * p) * 2560 + r;
    size_t i1 = i0 + 2560;
    h2 h0 = uph(h_all[i0]), h1 = uph(h_all[i1]);
    h2 cc0 = uph(c_all[i0]), cc1 = uph(c_all[i1]);
    h2 f0 = uph(f[(size_t)(2 * p) * 2560 + r]), f1 = uph(f[(size_t)(2 * p + 1) * 2560 + r]);
    hsum[t] = pkh((float)h0.x + (float)h1.x, (float)h0.y + (float)h1.y);
    cred[t] = pkh((float)f0.x * (float)cc0.x + (float)f1.x * (float)cc1.x,
                  (float)f0.y * (float)cc0.y + (float)f1.y * (float)cc1.y);
}

// LSTM cell on packed iou [P][15][512]; cin fp32 (leaves) or packed (internal)
template<bool CFP32>
__global__ __launch_bounds__(256) void treeapplyh(
    const unsigned* __restrict__ iou, const float* __restrict__ b_iou,
    const void* __restrict__ cin, unsigned* __restrict__ h_all,
    unsigned* __restrict__ c_all, int P, int nodeBase)
{
    int t = blockIdx.x * blockDim.x + threadIdx.x;
    if (t >= P * 512) return;
    int p = t / 512, s = t % 512;
    const unsigned* ip = iou + (size_t)p * 7680 + s;
    unsigned* hp = h_all + (size_t)(nodeBase + p) * 2560 + s;
    unsigned* cp = c_all + (size_t)(nodeBase + p) * 2560 + s;
#pragma unroll
    for (int q = 0; q < 5; ++q) {
        h2 iv = uph(ip[(size_t)q * 512]);
        h2 ov = uph(ip[(size_t)(5 + q) * 512]);
        h2 uv = uph(ip[(size_t)(10 + q) * 512]);
        float i0 = (float)iv.x + b_iou[(size_t)(2 * q) * 512 + s];
        float i1 = (float)iv.y + b_iou[(size_t)(2 * q + 1) * 512 + s];
        float o0 = (float)ov.x + b_iou[(size_t)(10 + 2 * q) * 512 + s];
        float o1 = (float)ov.y + b_iou[(size_t)(10 + 2 * q + 1) * 512 + s];
        float u0 = (float)uv.x + b_iou[(size_t)(20 + 2 * q) * 512 + s];
        float u1 = (float)uv.y + b_iou[(size_t)(20 + 2 * q + 1) * 512 + s];
        float c0v, c1v;
        if (CFP32) {
            const float* cf = (const float*)cin + ((size_t)p * 10 + 2 * q) * 512 + s;
            c0v = cf[0]; c1v = cf[512];
        } else {
            h2 cv = uph(((const unsigned*)cin)[(size_t)p * 2560 + q * 512 + s]);
            c0v = (float)cv.x; c1v = (float)cv.y;
        }
        float c0n = (1.f / (1.f + expf(-i0))) * tanhf(u0) + c0v;
        float c1n = (1.f / (1.f + expf(-i1))) * tanhf(u1) + c1v;
        float h0n = (1.f / (1.f + expf(-o0))) * tanhf(c0n);
        float h1n = (1.f / (1.f + expf(-o1))) * tanhf(c1n);
        hp[(size_t)q * 512] = pkh(h0n, h1n);
        cp[(size_t)q * 512] = pkh(c0n, c1n);
    }
}

// d1c: 1x1x1 conv 16->1 (packed input, fp32 output)
__global__ __launch_bounds__(256) void conv1x1h(
    const unsigned* __restrict__ in, const float* __restrict__ w,
    const float* __restrict__ b, float* __restrict__ out, int total)
{
    int t = blockIdx.x * blockDim.x + threadIdx.x;
    if (t >= total) return;
    int n = t / 32768, s = t % 32768;
    const unsigned* p = in + (size_t)n * 8 * 32768 + s;
    float a = b[0];
#pragma unroll
    for (int q = 0; q < 8; ++q) {
        h2 x = uph(p[(size_t)q * 32768]);
        a = fmaf((float)x.x, w[2 * q], fmaf((float)x.y, w[2 * q + 1], a));
    }
    out[t] = a;
}

extern "C" void kernel_launch(void* const* d_in, const int* in_sizes, int n_in,
                              void* d_out, int out_size, void* d_ws, size_t ws_size,
                              hipStream_t stream)
{
    const float* data  = (const float*)d_in[0];
    const float* c0    = (const float*)d_in[2];
    const float* e1a_w = (const float*)d_in[3];  const float* e1a_b = (const float*)d_in[4];
    const float* e1b_w = (const float*)d_in[5];  const float* e1b_b = (const float*)d_in[6];
    const float* e2a_w = (const float*)d_in[7];  const float* e2a_b = (const float*)d_in[8];
    const float* e2b_w = (const float*)d_in[9];  const float* e2b_b = (const float*)d_in[10];
    const float* d2a_w = (const float*)d_in[11]; const float* d2a_b = (const float*)d_in[12];
    const float* d2b_w = (const float*)d_in[13]; const float* d2b_b = (const float*)d_in[14];
    const float* d1a_w = (const float*)d_in[15]; const float* d1a_b = (const float*)d_in[16];
    const float* d1b_w = (const float*)d_in[17]; const float* d1b_b = (const float*)d_in[18];
    const float* d1c_w = (const float*)d_in[19]; const float* d1c_b = (const float*)d_in[20];
    const float* w_iou = (const float*)d_in[21];
    const float* u_iou = (const float*)d_in[22];
    const float* u_f   = (const float*)d_in[23];
    const float* b_iou = (const float*)d_in[24];

    unsigned* ws = (unsigned*)d_ws;
    size_t o = 0;
    unsigned* t1   = ws + o; o += 8126464;   // [31,8p,32^3]  (reused as t4)
    unsigned* x0   = ws + o; o += 8126464;   // [31,8p,32^3]  (reused as t5)
    unsigned* xp   = ws + o; o += 1015808;   // [31,8p,16^3]
    unsigned* t2   = ws + o; o += 2031616;   // [31,16p,16^3] (reused as t3 [31,10p,16^3])
    unsigned* x1   = ws + o; o += 1269760;   // [31,10p,16^3]
    unsigned* xp2  = ws + o; o += 158720;    // [31,10p,8^3]
    unsigned* Wx   = ws + o; o += 122880;    // [16,15p,8^3]
    unsigned* h_all= ws + o; o += 79360;     // [31,5p,8^3]
    unsigned* c_all= ws + o; o += 79360;
    unsigned* f_buf= ws + o; o += 40960;     // [16,5p,8^3]
    unsigned* hsum = ws + o; o += 20480;     // [8,5p,8^3]
    unsigned* cred = ws + o; o += 20480;
    unsigned* ioub = ws + o; o += 61440;     // [8,15p,8^3]
    unsigned* y2   = ws + o; o += 2031616;   // [31,16p,16^3]
    unsigned* t3 = t2;
    unsigned* t4 = t1;
    unsigned* t5 = x0;
    (void)ws_size; (void)in_sizes; (void)n_in; (void)out_size;

    dim3 b256(256), b128(128);

    // ---- Encoder ----
    conv3e1a<<<dim3(31 * 32), b256, 0, stream>>>(data, e1a_w, e1a_b, t1);
    conv3h<8, 16, 0, 32, 16, 8, ACT_RELU, true>
        <<<dim3(31 * 32, 1), b256, 0, stream>>>(nullptr, t1, e1b_w, e1b_b, x0);
    maxpoolh<<<dim3((1015808 + 255) / 256), b256, 0, stream>>>(x0, xp, 1015808, 16);
    conv3h<8, 32, 0, 16, 16, 8, ACT_RELU, true>
        <<<dim3(31 * 4, 2), b256, 0, stream>>>(nullptr, xp, e2a_w, e2a_b, t2);
    conv3h<16, 20, 0, 16, 10, 16, ACT_RELU, true>
        <<<dim3(31 * 4, 2), b256, 0, stream>>>(nullptr, t2, e2b_w, e2b_b, x1);
    maxpoolh<<<dim3((158720 + 255) / 256), b256, 0, stream>>>(x1, xp2, 158720, 8);

    // ---- leaves (xp2 node stride = 10 pairs * 512 = 5120) ----
    conv3h<10, 30, 0, 8, 10, 10, ACT_NONE, false>
        <<<dim3(16, 3), b128, 0, stream>>>(nullptr, xp2 + (size_t)15 * 5120, w_iou, nullptr, Wx);
    treeapplyh<true><<<dim3((16 * 512 + 255) / 256), b256, 0, stream>>>(
        Wx, b_iou, c0 + (size_t)15 * 10 * 512, h_all, c_all, 16, 15);

    // ---- internal levels, bottom-up ----
    for (int lvl = 3; lvl >= 0; --lvl) {
        int P  = 1 << lvl;
        int cb = (1 << (lvl + 1)) - 1;
        int pb = (1 << lvl) - 1;
        conv3h<5, 10, 0, 8, 10, 5, ACT_SIG, false>
            <<<dim3(2 * P, 1), b128, 0, stream>>>(nullptr, h_all + (size_t)cb * 2560, u_f, nullptr, f_buf);
        treereduceh<<<dim3((P * 2560 + 255) / 256), b256, 0, stream>>>(
            h_all, c_all, f_buf, hsum, cred, P, cb);
        conv3h<5, 30, 0, 8, 10, 5, ACT_NONE, false>
            <<<dim3(P, 3), b128, 0, stream>>>(nullptr, hsum, u_iou, nullptr, ioub);
        treeapplyh<false><<<dim3((P * 512 + 255) / 256), b256, 0, stream>>>(
            ioub, b_iou, cred, h_all, c_all, P, pb);
    }

    // ---- Decoder (fused up2 + concat in conv fetch) ----
    conv3h<15, 20, 5, 16, 10, 15, ACT_RELU, true>
        <<<dim3(31 * 4, 2), b256, 0, stream>>>(h_all, x1, d2a_w, d2a_b, t3);
    conv3h<10, 32, 0, 16, 16, 10, ACT_RELU, true>
        <<<dim3(31 * 4, 2), b256, 0, stream>>>(nullptr, t3, d2b_w, d2b_b, y2);
    conv3h<24, 16, 16, 32, 16, 8, ACT_RELU, true>
        <<<dim3(31 * 32, 1), b256, 0, stream>>>(y2, x0, d1a_w, d1a_b, t4);
    conv3h<8, 16, 0, 32, 16, 8, ACT_RELU, true>
        <<<dim3(31 * 32, 1), b256, 0, stream>>>(nullptr, t4, d1b_w, d1b_b, t5);
    conv1x1h<<<dim3((31 * 32768 + 255) / 256), b256, 0, stream>>>(
        t5, d1c_w, d1c_b, (float*)d_out, 31 * 32768);
}

// Round 4
// 1246.191 us; speedup vs baseline: 1.6647x; 1.1254x over previous
//
#include <hip/hip_runtime.h>
#include <math.h>

#define ACT_NONE 0
#define ACT_RELU 1
#define ACT_SIG  2

typedef _Float16 h2 __attribute__((ext_vector_type(2)));
typedef _Float16 half4_t __attribute__((ext_vector_type(4)));
typedef float f32x4 __attribute__((ext_vector_type(4)));

__device__ inline h2 uph(unsigned u) { return __builtin_bit_cast(h2, u); }
__device__ inline unsigned pkh(float a, float b) {
    return __builtin_bit_cast(unsigned, __builtin_amdgcn_cvt_pkrtz(a, b));
}
__device__ inline float dot2(unsigned a, unsigned b, float c) {
    return __builtin_amdgcn_fdot2(uph(a), uph(b), c, false);
}

// ============================================================================
// MFMA implicit-GEMM 3x3x3 conv, D=32, CO=16, pad=1, relu, packed half2 I/O.
// Block = (n, d, 8-row h-band): M=256 outputs x N=16 co.
// K = CI*27 split as 27 taps x 16-ci chunks -> v_mfma_f32_16x16x16f16 each.
// UPP pairs come from `up` at 16^3 (fused nearest-upsample), rest from `src`.
// LDS: raw input window [3][10][34][ci16 pad20] f16 + B[tap][co][ci16] f16.
// Layouts (guide-verified 16x16 family): A[m=lane&15][k=quad*4+j],
// B[n=lane&15][k=quad*4+j], C col=lane&15, row=quad*4+reg.
// ============================================================================
template<int CIP, int UPP>
__global__ __launch_bounds__(256) void conv3m(
    const unsigned* __restrict__ up, const unsigned* __restrict__ src,
    const float* __restrict__ wgt, const float* __restrict__ bias,
    unsigned* __restrict__ out)
{
    constexpr int NCH = CIP / 8;       // ci chunks of 8 pairs (16 ci)
    constexpr int CI  = CIP * 2;
    constexpr int SP  = CIP - UPP;     // full-res source pairs

    __shared__ _Float16 win[3 * 10 * 34 * 20];
    __shared__ _Float16 bw[27 * 16 * 16];

    const int tid = threadIdx.x;
    const int bx  = blockIdx.x;
    const int hb  = bx & 3;
    const int d   = (bx >> 2) & 31;
    const int n   = bx >> 7;
    const int h0  = hb * 8;

    const int lane = tid & 63;
    const int wv   = tid >> 6;
    const int l16  = lane & 15;
    const int quad = lane >> 4;

    f32x4 acc[4];
    {
        float b0 = bias[l16];          // col = co = lane&15
        for (int i = 0; i < 4; ++i) acc[i] = f32x4{b0, b0, b0, b0};
    }

    const int sp  = tid >> 5;          // pair-in-chunk 0..7
    const int col = tid & 31;          // w-column 0..31

    for (int cib = 0; cib < NCH; ++cib) {
        // ---- stage B: bw[tap][co][ci] = (f16) wgt[co][cib*16+ci][tap] ----
        {
            const int bco = tid >> 4;
            const int bci = tid & 15;
#pragma unroll
            for (int tap = 0; tap < 27; ++tap)
                bw[(tap * 16 + bco) * 16 + bci] =
                    (_Float16)wgt[((size_t)bco * CI + cib * 16 + bci) * 27 + tap];
        }
        // ---- stage A window (u32 pair writes) ----
        {
            const int p = cib * 8 + sp;    // global pair index
#pragma unroll
            for (int dp = 0; dp < 3; ++dp) {
                const int zd = d - 1 + dp;
                const bool dok = (unsigned)zd < 32u;
#pragma unroll
                for (int hh = 0; hh < 10; ++hh) {
                    const int zh = h0 + hh - 1;
                    const bool ok = dok && ((unsigned)zh < 32u);
                    unsigned v1 = 0, v2 = 0;
                    if (ok) {
                        // ww = col -> zw = col-1 ; ww = 32+col (col<2) -> zw = 31+col
                        if (UPP > 0 && p < UPP) {
                            const unsigned* b = up +
                                ((size_t)(n * UPP + p) * 16 + (zd >> 1)) * 256 + (zh >> 1) * 16;
                            if (col > 0) v1 = b[(col - 1) >> 1];
                            if (col == 0) v2 = b[15];
                        } else {
                            const unsigned* b = src +
                                ((size_t)(n * SP + (p - UPP)) * 32 + zd) * 1024 + zh * 32;
                            if (col > 0) v1 = b[col - 1];
                            if (col == 0) v2 = b[31];
                        }
                    }
                    const int base = ((dp * 10 + hh) * 34) * 20 + 2 * sp;
                    *(unsigned*)&win[base + col * 20] = v1;
                    if (col < 2) *(unsigned*)&win[base + (32 + col) * 20] = v2;
                }
            }
        }
        __syncthreads();

        // ---- 27 taps x 4 m-tiles of MFMA ----
#pragma unroll
        for (int kd = 0; kd < 3; ++kd) {
#pragma unroll
            for (int kh = 0; kh < 3; ++kh) {
#pragma unroll
                for (int kw = 0; kw < 3; ++kw) {
                    const int tap = (kd * 3 + kh) * 3 + kw;
                    half4_t bf = *(const half4_t*)&bw[(tap * 16 + l16) * 16 + quad * 4];
#pragma unroll
                    for (int i = 0; i < 4; ++i) {
                        const int mt = wv * 4 + i;
                        const int hl = mt >> 1;
                        const int ww = (mt & 1) * 16 + l16 + kw;
                        half4_t af = *(const half4_t*)
                            &win[((kd * 10 + hl + kh) * 34 + ww) * 20 + quad * 4];
                        acc[i] = __builtin_amdgcn_mfma_f32_16x16x16f16(af, bf, acc[i], 0, 0, 0);
                    }
                }
            }
        }
        __syncthreads();
    }

    // ---- epilogue: relu, scalar f16 stores into packed pair layout ----
    _Float16* outh = (_Float16*)out;
    const int co = l16;
#pragma unroll
    for (int i = 0; i < 4; ++i) {
        const int mt = wv * 4 + i;
        const int hl = mt >> 1;
        const int wb = (mt & 1) * 16;
#pragma unroll
        for (int r = 0; r < 4; ++r) {
            const int w = wb + quad * 4 + r;
            float v = fmaxf(acc[i][r], 0.f);
            size_t idx = ((((size_t)(n * 8 + (co >> 1)) * 32 + d) * 32 + (h0 + hl)) * 32 + w) * 2
                         + (co & 1);
            outh[idx] = (_Float16)v;
        }
    }
}

// ============================================================================
// dot2 direct conv (unchanged from round 3) — used for 16^3 / 8^3 convs
// ============================================================================
template<int CIP, int CO, int CIUPP, int D, int COC, int CICP, int ACT, bool BIAS>
__global__ __launch_bounds__(256) void conv3h(
    const unsigned* __restrict__ up, const unsigned* __restrict__ src,
    const float* __restrict__ wgt, const float* __restrict__ bias,
    unsigned* __restrict__ out)
{
    constexpr int WQ = (D == 32) ? 8 : (D == 16) ? 4 : 2;
    constexpr int TH = (D == 32) ? 32 : (D == 16) ? 16 : 8;
    constexpr int TD = (D == 32) ? 1 : (D == 16) ? 4 : 8;
    constexpr int NT = WQ * TH * TD;
    constexpr int DBLK = D / TD;
    constexpr int CI = CIP * 2;
    constexpr int DH = D / 2;

    __shared__ unsigned sw[CICP * 27 * COC];

    const int tid = threadIdx.x;
    const int wq = tid % WQ;
    const int h  = (tid / WQ) % TH;
    const int dz = tid / (WQ * TH);
    const int w0 = wq * 4;

    const int bx   = blockIdx.x;
    const int n    = bx / DBLK;
    const int dblk = bx % DBLK;
    const int d    = dblk * TD + dz;
    const int cob  = blockIdx.y * COC;

    float acc[COC][4];
#pragma unroll
    for (int co = 0; co < COC; ++co) {
        float b0 = 0.f;
        if (BIAS) { int cg = cob + co; if (cg < CO) b0 = bias[cg]; }
        acc[co][0] = b0; acc[co][1] = b0; acc[co][2] = b0; acc[co][3] = b0;
    }

    for (int cib = 0; cib < CIP; cib += CICP) {
        __syncthreads();
        for (int t = tid; t < CICP * 27 * COC; t += NT) {
            int co   = t % COC;
            int r    = t / COC;
            int tap  = r % 27;
            int cilp = r / 27;
            int cg   = cob + co;
            int ci0  = 2 * (cib + cilp);
            unsigned v = 0;
            if (cg < CO) {
                float w0f = wgt[((size_t)cg * CI + ci0) * 27 + tap];
                float w1f = wgt[((size_t)cg * CI + ci0 + 1) * 27 + tap];
                v = pkh(w0f, w1f);
            }
            sw[t] = v;
        }
        __syncthreads();

        for (int cilp = 0; cilp < CICP; ++cilp) {
            const int cip = cib + cilp;
#pragma unroll
            for (int kd = 0; kd < 3; ++kd) {
                int zd = d + kd - 1;
                if ((unsigned)zd >= (unsigned)D) continue;
#pragma unroll
                for (int kh = 0; kh < 3; ++kh) {
                    int zh = h + kh - 1;
                    if ((unsigned)zh >= (unsigned)D) continue;
                    unsigned v[6];
                    if (CIUPP > 0 && cip < CIUPP) {
                        const unsigned* p = up +
                            (((size_t)(n * CIUPP + cip) * DH + (zd >> 1)) * DH + (zh >> 1)) * DH;
#pragma unroll
                        for (int j = 0; j < 6; ++j) {
                            int zw = w0 - 1 + j;
                            v[j] = ((unsigned)zw < (unsigned)D) ? p[zw >> 1] : 0u;
                        }
                    } else {
                        const unsigned* p = src +
                            (((size_t)(n * (CIP - CIUPP) + (cip - CIUPP)) * D + zd) * D + zh) * D;
#pragma unroll
                        for (int j = 0; j < 6; ++j) {
                            int zw = w0 - 1 + j;
                            v[j] = ((unsigned)zw < (unsigned)D) ? p[zw] : 0u;
                        }
                    }
                    const unsigned* swp = &sw[(cilp * 27 + kd * 9 + kh * 3) * COC];
#pragma unroll
                    for (int kw = 0; kw < 3; ++kw) {
#pragma unroll
                        for (int co = 0; co < COC; ++co) {
                            unsigned wv = swp[kw * COC + co];
#pragma unroll
                            for (int j = 0; j < 4; ++j)
                                acc[co][j] = dot2(v[kw + j], wv, acc[co][j]);
                        }
                    }
                }
            }
        }
    }

#pragma unroll
    for (int cp = 0; cp < COC / 2; ++cp) {
        int cg = cob + 2 * cp;
        if (cg < CO) {
            unsigned r[4];
#pragma unroll
            for (int j = 0; j < 4; ++j) {
                float x0 = acc[2 * cp][j], x1 = acc[2 * cp + 1][j];
                if (ACT == ACT_RELU) { x0 = fmaxf(x0, 0.f); x1 = fmaxf(x1, 0.f); }
                else if (ACT == ACT_SIG) {
                    x0 = 1.f / (1.f + expf(-x0)); x1 = 1.f / (1.f + expf(-x1));
                }
                r[j] = pkh(x0, x1);
            }
            unsigned* op = out + ((size_t)(n * (CO / 2) + (cg >> 1)) * D + d) * D * D + h * D + w0;
            *reinterpret_cast<uint4*>(op) = make_uint4(r[0], r[1], r[2], r[3]);
        }
    }
}

// e1a: 1 fp32 input channel -> 16 channels (8 pairs packed), D=32
__global__ __launch_bounds__(256) void conv3e1a(
    const float* __restrict__ src, const float* __restrict__ wgt,
    const float* __restrict__ bias, unsigned* __restrict__ out)
{
    __shared__ float sw[27 * 16];
    const int tid = threadIdx.x;
    const int wq = tid % 8;
    const int h  = (tid / 8) % 32;
    const int w0 = wq * 4;
    const int n  = blockIdx.x / 32;
    const int d  = blockIdx.x % 32;

    for (int t = tid; t < 27 * 16; t += 256) {
        int co = t % 16, tap = t / 16;
        sw[t] = wgt[(size_t)co * 27 + tap];
    }
    __syncthreads();

    float acc[16][4];
#pragma unroll
    for (int co = 0; co < 16; ++co) {
        float b0 = bias[co];
        acc[co][0] = b0; acc[co][1] = b0; acc[co][2] = b0; acc[co][3] = b0;
    }

#pragma unroll
    for (int kd = 0; kd < 3; ++kd) {
        int zd = d + kd - 1;
        if ((unsigned)zd >= 32u) continue;
#pragma unroll
        for (int kh = 0; kh < 3; ++kh) {
            int zh = h + kh - 1;
            if ((unsigned)zh >= 32u) continue;
            const float* p = src + ((size_t)n * 32 + zd) * 1024 + zh * 32;
            float v[6];
#pragma unroll
            for (int j = 0; j < 6; ++j) {
                int zw = w0 - 1 + j;
                v[j] = ((unsigned)zw < 32u) ? p[zw] : 0.f;
            }
            const float* swp = &sw[(kd * 9 + kh * 3) * 16];
#pragma unroll
            for (int kw = 0; kw < 3; ++kw)
#pragma unroll
                for (int co = 0; co < 16; ++co)
#pragma unroll
                    for (int j = 0; j < 4; ++j)
                        acc[co][j] = fmaf(v[kw + j], swp[kw * 16 + co], acc[co][j]);
        }
    }

#pragma unroll
    for (int cp = 0; cp < 8; ++cp) {
        unsigned r[4];
#pragma unroll
        for (int j = 0; j < 4; ++j)
            r[j] = pkh(fmaxf(acc[2 * cp][j], 0.f), fmaxf(acc[2 * cp + 1][j], 0.f));
        unsigned* op = out + ((size_t)(n * 8 + cp) * 32 + d) * 1024 + h * 32 + w0;
        *reinterpret_cast<uint4*>(op) = make_uint4(r[0], r[1], r[2], r[3]);
    }
}

// 2x2x2 maxpool on packed half2 arrays
__global__ __launch_bounds__(256) void maxpoolh(
    const unsigned* __restrict__ in, unsigned* __restrict__ out, int total, int Do)
{
    int t = blockIdx.x * blockDim.x + threadIdx.x;
    if (t >= total) return;
    int w = t % Do; int r = t / Do;
    int h = r % Do; r /= Do;
    int d = r % Do; int nc = r / Do;
    int Di = Do * 2;
    const unsigned* p = in + (((size_t)nc * Di + 2 * d) * Di + 2 * h) * Di + 2 * w;
    float m0 = -1e30f, m1 = -1e30f;
#pragma unroll
    for (int a = 0; a < 2; ++a)
#pragma unroll
        for (int b = 0; b < 2; ++b)
#pragma unroll
            for (int c = 0; c < 2; ++c) {
                h2 x = uph(p[((size_t)a * Di + b) * Di + c]);
                m0 = fmaxf(m0, (float)x.x);
                m1 = fmaxf(m1, (float)x.y);
            }
    out[t] = pkh(m0, m1);
}

// hsum[p] = h[c0]+h[c1]; cred[p] = f[2p]*c[c0] + f[2p+1]*c[c1]  (packed half2)
__global__ __launch_bounds__(256) void treereduceh(
    const unsigned* __restrict__ h_all, const unsigned* __restrict__ c_all,
    const unsigned* __restrict__ f, unsigned* __restrict__ hsum,
    unsigned* __restrict__ cred, int P, int cb)
{
    int t = blockIdx.x * blockDim.x + threadIdx.x;
    if (t >= P * 2560) return;
    int p = t / 2560, r = t % 2560;
    size_t i0 = (size_t)(cb + 2 * p) * 2560 + r;
    size_t i1 = i0 + 2560;
    h2 h0 = uph(h_all[i0]), h1 = uph(h_all[i1]);
    h2 cc0 = uph(c_all[i0]), cc1 = uph(c_all[i1]);
    h2 f0 = uph(f[(size_t)(2 * p) * 2560 + r]), f1 = uph(f[(size_t)(2 * p + 1) * 2560 + r]);
    hsum[t] = pkh((float)h0.x + (float)h1.x, (float)h0.y + (float)h1.y);
    cred[t] = pkh((float)f0.x * (float)cc0.x + (float)f1.x * (float)cc1.x,
                  (float)f0.y * (float)cc0.y + (float)f1.y * (float)cc1.y);
}

// LSTM cell on packed iou [P][15][512]; cin fp32 (leaves) or packed (internal)
template<bool CFP32>
__global__ __launch_bounds__(256) void treeapplyh(
    const unsigned* __restrict__ iou, const float* __restrict__ b_iou,
    const void* __restrict__ cin, unsigned* __restrict__ h_all,
    unsigned* __restrict__ c_all, int P, int nodeBase)
{
    int t = blockIdx.x * blockDim.x + threadIdx.x;
    if (t >= P * 512) return;
    int p = t / 512, s = t % 512;
    const unsigned* ip = iou + (size_t)p * 7680 + s;
    unsigned* hp = h_all + (size_t)(nodeBase + p) * 2560 + s;
    unsigned* cp = c_all + (size_t)(nodeBase + p) * 2560 + s;
#pragma unroll
    for (int q = 0; q < 5; ++q) {
        h2 iv = uph(ip[(size_t)q * 512]);
        h2 ov = uph(ip[(size_t)(5 + q) * 512]);
        h2 uv = uph(ip[(size_t)(10 + q) * 512]);
        float i0 = (float)iv.x + b_iou[(size_t)(2 * q) * 512 + s];
        float i1 = (float)iv.y + b_iou[(size_t)(2 * q + 1) * 512 + s];
        float o0 = (float)ov.x + b_iou[(size_t)(10 + 2 * q) * 512 + s];
        float o1 = (float)ov.y + b_iou[(size_t)(10 + 2 * q + 1) * 512 + s];
        float u0 = (float)uv.x + b_iou[(size_t)(20 + 2 * q) * 512 + s];
        float u1 = (float)uv.y + b_iou[(size_t)(20 + 2 * q + 1) * 512 + s];
        float c0v, c1v;
        if (CFP32) {
            const float* cf = (const float*)cin + ((size_t)p * 10 + 2 * q) * 512 + s;
            c0v = cf[0]; c1v = cf[512];
        } else {
            h2 cv = uph(((const unsigned*)cin)[(size_t)p * 2560 + q * 512 + s]);
            c0v = (float)cv.x; c1v = (float)cv.y;
        }
        float c0n = (1.f / (1.f + expf(-i0))) * tanhf(u0) + c0v;
        float c1n = (1.f / (1.f + expf(-i1))) * tanhf(u1) + c1v;
        float h0n = (1.f / (1.f + expf(-o0))) * tanhf(c0n);
        float h1n = (1.f / (1.f + expf(-o1))) * tanhf(c1n);
        hp[(size_t)q * 512] = pkh(h0n, h1n);
        cp[(size_t)q * 512] = pkh(c0n, c1n);
    }
}

// d1c: 1x1x1 conv 16->1 (packed input, fp32 output)
__global__ __launch_bounds__(256) void conv1x1h(
    const unsigned* __restrict__ in, const float* __restrict__ w,
    const float* __restrict__ b, float* __restrict__ out, int total)
{
    int t = blockIdx.x * blockDim.x + threadIdx.x;
    if (t >= total) return;
    int n = t / 32768, s = t % 32768;
    const unsigned* p = in + (size_t)n * 8 * 32768 + s;
    float a = b[0];
#pragma unroll
    for (int q = 0; q < 8; ++q) {
        h2 x = uph(p[(size_t)q * 32768]);
        a = fmaf((float)x.x, w[2 * q], fmaf((float)x.y, w[2 * q + 1], a));
    }
    out[t] = a;
}

extern "C" void kernel_launch(void* const* d_in, const int* in_sizes, int n_in,
                              void* d_out, int out_size, void* d_ws, size_t ws_size,
                              hipStream_t stream)
{
    const float* data  = (const float*)d_in[0];
    const float* c0    = (const float*)d_in[2];
    const float* e1a_w = (const float*)d_in[3];  const float* e1a_b = (const float*)d_in[4];
    const float* e1b_w = (const float*)d_in[5];  const float* e1b_b = (const float*)d_in[6];
    const float* e2a_w = (const float*)d_in[7];  const float* e2a_b = (const float*)d_in[8];
    const float* e2b_w = (const float*)d_in[9];  const float* e2b_b = (const float*)d_in[10];
    const float* d2a_w = (const float*)d_in[11]; const float* d2a_b = (const float*)d_in[12];
    const float* d2b_w = (const float*)d_in[13]; const float* d2b_b = (const float*)d_in[14];
    const float* d1a_w = (const float*)d_in[15]; const float* d1a_b = (const float*)d_in[16];
    const float* d1b_w = (const float*)d_in[17]; const float* d1b_b = (const float*)d_in[18];
    const float* d1c_w = (const float*)d_in[19]; const float* d1c_b = (const float*)d_in[20];
    const float* w_iou = (const float*)d_in[21];
    const float* u_iou = (const float*)d_in[22];
    const float* u_f   = (const float*)d_in[23];
    const float* b_iou = (const float*)d_in[24];

    unsigned* ws = (unsigned*)d_ws;
    size_t o = 0;
    unsigned* t1   = ws + o; o += 8126464;   // [31,8p,32^3]  (reused as t4)
    unsigned* x0   = ws + o; o += 8126464;   // [31,8p,32^3]  (reused as t5)
    unsigned* xp   = ws + o; o += 1015808;   // [31,8p,16^3]
    unsigned* t2   = ws + o; o += 2031616;   // [31,16p,16^3] (reused as t3 [31,10p,16^3])
    unsigned* x1   = ws + o; o += 1269760;   // [31,10p,16^3]
    unsigned* xp2  = ws + o; o += 158720;    // [31,10p,8^3]
    unsigned* Wx   = ws + o; o += 122880;    // [16,15p,8^3]
    unsigned* h_all= ws + o; o += 79360;     // [31,5p,8^3]
    unsigned* c_all= ws + o; o += 79360;
    unsigned* f_buf= ws + o; o += 40960;     // [16,5p,8^3]
    unsigned* hsum = ws + o; o += 20480;     // [8,5p,8^3]
    unsigned* cred = ws + o; o += 20480;
    unsigned* ioub = ws + o; o += 61440;     // [8,15p,8^3]
    unsigned* y2   = ws + o; o += 2031616;   // [31,16p,16^3]
    unsigned* t3 = t2;
    unsigned* t4 = t1;
    unsigned* t5 = x0;
    (void)ws_size; (void)in_sizes; (void)n_in; (void)out_size;

    dim3 b256(256), b128(128);

    // ---- Encoder ----
    conv3e1a<<<dim3(31 * 32), b256, 0, stream>>>(data, e1a_w, e1a_b, t1);
    conv3m<8, 0><<<dim3(31 * 32 * 4), b256, 0, stream>>>(nullptr, t1, e1b_w, e1b_b, x0);
    maxpoolh<<<dim3((1015808 + 255) / 256), b256, 0, stream>>>(x0, xp, 1015808, 16);
    conv3h<8, 32, 0, 16, 16, 8, ACT_RELU, true>
        <<<dim3(31 * 4, 2), b256, 0, stream>>>(nullptr, xp, e2a_w, e2a_b, t2);
    conv3h<16, 20, 0, 16, 10, 16, ACT_RELU, true>
        <<<dim3(31 * 4, 2), b256, 0, stream>>>(nullptr, t2, e2b_w, e2b_b, x1);
    maxpoolh<<<dim3((158720 + 255) / 256), b256, 0, stream>>>(x1, xp2, 158720, 8);

    // ---- leaves (xp2 node stride = 10 pairs * 512 = 5120) ----
    conv3h<10, 30, 0, 8, 10, 10, ACT_NONE, false>
        <<<dim3(16, 3), b128, 0, stream>>>(nullptr, xp2 + (size_t)15 * 5120, w_iou, nullptr, Wx);
    treeapplyh<true><<<dim3((16 * 512 + 255) / 256), b256, 0, stream>>>(
        Wx, b_iou, c0 + (size_t)15 * 10 * 512, h_all, c_all, 16, 15);

    // ---- internal levels, bottom-up ----
    for (int lvl = 3; lvl >= 0; --lvl) {
        int P  = 1 << lvl;
        int cb = (1 << (lvl + 1)) - 1;
        int pb = (1 << lvl) - 1;
        conv3h<5, 10, 0, 8, 10, 5, ACT_SIG, false>
            <<<dim3(2 * P, 1), b128, 0, stream>>>(nullptr, h_all + (size_t)cb * 2560, u_f, nullptr, f_buf);
        treereduceh<<<dim3((P * 2560 + 255) / 256), b256, 0, stream>>>(
            h_all, c_all, f_buf, hsum, cred, P, cb);
        conv3h<5, 30, 0, 8, 10, 5, ACT_NONE, false>
            <<<dim3(P, 3), b128, 0, stream>>>(nullptr, hsum, u_iou, nullptr, ioub);
        treeapplyh<false><<<dim3((P * 512 + 255) / 256), b256, 0, stream>>>(
            ioub, b_iou, cred, h_all, c_all, P, pb);
    }

    // ---- Decoder (fused up2 + concat in conv fetch) ----
    conv3h<15, 20, 5, 16, 10, 15, ACT_RELU, true>
        <<<dim3(31 * 4, 2), b256, 0, stream>>>(h_all, x1, d2a_w, d2a_b, t3);
    conv3h<10, 32, 0, 16, 16, 10, ACT_RELU, true>
        <<<dim3(31 * 4, 2), b256, 0, stream>>>(nullptr, t3, d2b_w, d2b_b, y2);
    conv3m<24, 16><<<dim3(31 * 32 * 4), b256, 0, stream>>>(y2, x0, d1a_w, d1a_b, t4);
    conv3m<8, 0><<<dim3(31 * 32 * 4), b256, 0, stream>>>(nullptr, t4, d1b_w, d1b_b, t5);
    conv1x1h<<<dim3((31 * 32768 + 255) / 256), b256, 0, stream>>>(
        t5, d1c_w, d1c_b, (float*)d_out, 31 * 32768);
}